// Round 13
// baseline (254.220 us; speedup 1.0000x reference)
//
#include <hip/hip_runtime.h>

typedef float f32x4 __attribute__((ext_vector_type(4)));
typedef unsigned int uint32;
typedef unsigned long long uint64;

#define LPAD 512     // per-column staging (L=400 fits)
#define LPG  4096    // pg LDS cache capacity (rows=2048 fits)

// ---------------------------------------------------------------------------
// Prep (B blocks): per source column b
//   1. (v,l) rank-sort ascending by (v,l)            [O(L^2), LDS]
//   2. dedup keep-LAST-occurrence (scatter .set semantics), drop OOB ids
//   3. emit unique lists uv/ul + count nu[b]
// ---------------------------------------------------------------------------
__global__ __launch_bounds__(256) void prep_kernel(
    const int* __restrict__ sources, int* __restrict__ uv, int* __restrict__ ul,
    int* __restrict__ nu, int L, int B, int V)
{
    const int b = blockIdx.x;
    __shared__ int s_col[LPAD];
    __shared__ int s_sv[LPAD];
    __shared__ int s_sl[LPAD];
    __shared__ int s_cnt;
    if (threadIdx.x == 0) s_cnt = 0;

    for (int l = threadIdx.x; l < L; l += 256) {
        const int v = sources[(size_t)l * B + b];
        s_col[l] = (v >= 0 && v < V) ? v : 0x7FFFFFFF;   // mode="drop"
    }
    __syncthreads();

    for (int l = threadIdx.x; l < L; l += 256) {
        const int v = s_col[l];
        int rank = 0;
        for (int k = 0; k < L; ++k) {
            const int vk = s_col[k];
            rank += (vk < v) || (vk == v && k < l);
        }
        s_sv[rank] = v;
        s_sl[rank] = l;
    }
    __syncthreads();

    // survivor = last of each equal-v run, with valid v. pos = prefix rank.
    int* __restrict__ uvb = uv + (size_t)b * L;
    int* __restrict__ ulb = ul + (size_t)b * L;
    for (int t = threadIdx.x; t < L; t += 256) {
        const int v = s_sv[t];
        const bool surv = (v < V) && (t == L - 1 || s_sv[t + 1] != v);
        if (surv) {
            int pos = 0;
            for (int k = 0; k < t; ++k) {
                const int vk = s_sv[k];
                pos += (vk < V) && (s_sv[k + 1] != vk);   // k<t<=L-1 so k+1 ok
            }
            uvb[pos] = v;
            ulb[pos] = s_sl[t];
            atomicAdd(&s_cnt, 1);
        }
    }
    __syncthreads();
    if (threadIdx.x == 0) nu[b] = s_cnt;
}

// ---------------------------------------------------------------------------
// Flat pure-scale: out[g] = pg[row(g)] * vd[g], grid-stride tiles of 256
// f32x4. Tile s = t*gridDim + bid => all in-flight requests form one compact
// sliding window (copy/fill geometry). pg served from an LDS cache (no
// dependent global load in the hot chain); row via exact magic multiply.
// ---------------------------------------------------------------------------
__global__ __launch_bounds__(256) void scale_flat_kernel(
    const float* __restrict__ vd, const float* __restrict__ pgs,
    float* __restrict__ out, int V, int rows,
    uint64 magicM, long long ntiles, long long n4, long long total)
{
    __shared__ float s_pg[LPG];
    for (int r = threadIdx.x; r < rows; r += 256) s_pg[r] = pgs[r];
    __syncthreads();

    const int tid = threadIdx.x;

    for (long long s = blockIdx.x; s < ntiles; s += gridDim.x) {
        const long long g = ((s << 8) + tid) << 2;
        const uint32 row = (uint32)(((uint64)g * magicM) >> 48);
        const uint32 j   = (uint32)((uint64)g - (uint64)row * (uint32)V);
        f32x4 x = *(const f32x4*)(vd + g);
        if (j + 4u <= (uint32)V) {                    // whole vector in one row
            x *= s_pg[row];
            __builtin_nontemporal_store(x, (f32x4*)(out + g));
        } else {                                      // row-boundary vector
            f32x4 xo;
#pragma unroll
            for (int e = 0; e < 4; ++e) {
                const uint32 re = (j + e >= (uint32)V) ? row + 1 : row;
                xo[e] = x[e] * s_pg[re];
            }
            __builtin_nontemporal_store(xo, (f32x4*)(out + g));
        }
    }

    // leftover vectors + scalar tail (generic; empty for this problem's sizes)
    for (long long i4 = (ntiles << 8) + (long long)blockIdx.x * 256 + tid;
         i4 < n4; i4 += (long long)gridDim.x * 256) {
        const long long g = i4 << 2;
        const uint32 row = (uint32)(((uint64)g * magicM) >> 48);
        const uint32 j   = (uint32)((uint64)g - (uint64)row * (uint32)V);
        f32x4 x = *(const f32x4*)(vd + g);
        f32x4 xo;
#pragma unroll
        for (int e = 0; e < 4; ++e) {
            const uint32 re = (j + e >= (uint32)V) ? row + 1 : row;
            xo[e] = x[e] * s_pg[re];
        }
        __builtin_nontemporal_store(xo, (f32x4*)(out + g));
    }
    for (long long g = (n4 << 2) + (long long)blockIdx.x * 256 + tid;
         g < total; g += (long long)gridDim.x * 256) {
        const uint32 row = (uint32)(((uint64)g * magicM) >> 48);
        out[g] = s_pg[row] * vd[g];
    }
}

// ---------------------------------------------------------------------------
// Additive scatter: out[row, uv[t]] += (1-pg) * attns[row, ul[t]].
// Slots are unique per row (dedup'd) => no write conflicts. Runs after the
// scale pass (stream-ordered), so += lands on pg*vd — overwrite semantics
// out = pg*vd + gate*attn reproduced exactly.
// ---------------------------------------------------------------------------
__global__ __launch_bounds__(256) void scatter_add_kernel(
    const float* __restrict__ attns, const float* __restrict__ pgs,
    const int* __restrict__ uv, const int* __restrict__ ul,
    const int* __restrict__ nu, float* __restrict__ out, int V, int L, int B)
{
    const int row = blockIdx.x;
    const int b   = row % B;
    const int n   = nu[b];
    const float gate = 1.0f - pgs[row];
    const size_t base = (size_t)row * (size_t)V;
    const int* __restrict__ uvb = uv + (size_t)b * L;
    const int* __restrict__ ulb = ul + (size_t)b * L;
    for (int t = threadIdx.x; t < n; t += 256) {
        const int v = uvb[t];
        out[base + v] += gate * attns[(size_t)row * L + ulb[t]];
    }
}

// ---------------------------------------------------------------------------
// Fallback (round-1 fused kernel, verified correct) if sizes out of bounds.
// ---------------------------------------------------------------------------
__global__ __launch_bounds__(256) void fused_fallback_kernel(
    const float* __restrict__ vocab_ds, const float* __restrict__ attns,
    const float* __restrict__ p_gens, const int* __restrict__ sources,
    float* __restrict__ out, int V, int L, int B)
{
    const int row = blockIdx.x;
    const int tid = threadIdx.x;
    const size_t base = (size_t)row * (size_t)V;
    const float pg = p_gens[row];

    const int mis  = (int)(base & 3);
    const int pre  = mis ? (4 - mis) : 0;
    const int preN = pre < V ? pre : V;
    for (int j = tid; j < preN; j += blockDim.x)
        out[base + j] = pg * vocab_ds[base + j];
    const int nvec = (V - preN) >> 2;
    const f32x4* __restrict__ v4 = (const f32x4*)(vocab_ds + base + preN);
    f32x4* __restrict__ o4       = (f32x4*)(out + base + preN);
    for (int i = tid; i < nvec; i += blockDim.x) {
        f32x4 x = v4[i];
        x *= pg;
        o4[i] = x;
    }
    for (int j = preN + (nvec << 2) + tid; j < V; j += blockDim.x)
        out[base + j] = pg * vocab_ds[base + j];

    __shared__ int s_src[512];
    const int b = row % B;
    const bool use_lds = (L <= 512);
    if (use_lds) {
        for (int l = tid; l < L; l += blockDim.x)
            s_src[l] = sources[(size_t)l * B + b];
    }
    __syncthreads();
    const float gate = 1.0f - pg;
    for (int l = tid; l < L; l += blockDim.x) {
        const int v = use_lds ? s_src[l] : sources[(size_t)l * B + b];
        if (v < 0 || v >= V) continue;
        bool last = true;
        for (int l2 = l + 1; l2 < L; ++l2) {
            const int v2 = use_lds ? s_src[l2] : sources[(size_t)l2 * B + b];
            if (v2 == v) { last = false; break; }
        }
        if (last) {
            const float a = gate * attns[(size_t)row * L + l];
            out[base + v] = pg * vocab_ds[base + v] + a;
        }
    }
}

extern "C" void kernel_launch(void* const* d_in, const int* in_sizes, int n_in,
                              void* d_out, int out_size, void* d_ws, size_t ws_size,
                              hipStream_t stream) {
    const float* vocab_ds = (const float*)d_in[0];
    const float* attns    = (const float*)d_in[1];
    const float* p_gens   = (const float*)d_in[2];
    const int*   sources  = (const int*)d_in[3];
    const int rows = in_sizes[2];
    const int V    = in_sizes[0] / rows;
    const int L    = in_sizes[1] / rows;
    const int B    = in_sizes[3] / L;
    float* out = (float*)d_out;

    const size_t need = (size_t)B * (size_t)L * 2 * sizeof(int)
                      + (size_t)B * sizeof(int);
    const bool fits = (ws_size >= need) && (L <= LPAD) && (rows <= LPG) &&
                      ((long long)rows * V < (1ll << 40));
    if (fits) {
        int* uv = (int*)d_ws;
        int* ul = uv + (size_t)B * (size_t)L;
        int* nu = ul + (size_t)B * (size_t)L;

        const long long total  = (long long)rows * (long long)V;
        const long long n4     = total >> 2;
        const long long ntiles = n4 >> 8;
        const uint64 magicM =
            (uint64)((((__uint128_t)1) << 48) / (uint32)V) + 1ull;

        prep_kernel<<<B, 256, 0, stream>>>(sources, uv, ul, nu, L, B, V);
        scale_flat_kernel<<<2048, 256, 0, stream>>>(
            vocab_ds, p_gens, out, V, rows, magicM, ntiles, n4, total);
        scatter_add_kernel<<<rows, 256, 0, stream>>>(
            attns, p_gens, uv, ul, nu, out, V, L, B);
    } else {
        fused_fallback_kernel<<<rows, 256, 0, stream>>>(
            vocab_ds, attns, p_gens, sources, out, V, L, B);
    }
}